// Round 18
// baseline (342.704 us; speedup 1.0000x reference)
//
#include <hip/hip_runtime.h>

// Problem constants (fixed by the harness's setup_inputs)
#define NN 100000   // nodes
#define EE 1600000  // edges per relation
#define RR 4        // relations
#define FF 64       // feature size (in == out == 64)
#define NEDGE (RR * EE)

#define FB 64                         // fine bucket = 64 nodes
#define NB2 ((NN + FB - 1) / FB)      // 1563 fine buckets (dst>>6)
#define CAP 4608                      // fixed bucket capacity (mean 4096 + 8 sigma)
#define YB ((NN + 63) / 64)           // 1563 Y-GEMM blocks
#define CIB ((NB2 + 255) / 256)       // 7 cursor-init tail blocks
#define PC_B 512                      // passC blocks
#define PC_T 1024                     // passC threads
#define SEG (NEDGE / PC_B)            // 12500 edges per passC block (exact)
#define MAXJ ((SEG + PC_T - 1) / PC_T)  // 13 regs per thread
#define IDXBITS 19                    // plane*NN+src < 400000 < 2^19
#define IDXMASK ((1 << IDXBITS) - 1)
#define CH 2048                       // recs per LDS chunk in sort_gather

// ---------------------------------------------------------------------------
// Blocks [0,YB): Y[r][n][j] = sum_k inp[n][k]*W[r][k][j], bf16 out.
// inp rows are read DIRECTLY from global with wave-uniform addresses ->
// compiler emits scalar (s_load) reads; no LDS staging, no barrier. The
// 64 rows/block (16 KB) stay resident in L1/K$ for the 4 waves' re-reads.
// Blocks [YB,YB+CIB): cursorF[b] = b*CAP (ready before passC launches).
__global__ __launch_bounds__(256) void compute_y_init(const float* __restrict__ inp,
                                                      const float* __restrict__ W,
                                                      unsigned short* __restrict__ Y,
                                                      int* __restrict__ cursorF) {
    if (blockIdx.x >= YB) {
        const int i = (blockIdx.x - YB) * 256 + threadIdx.x;
        if (i < NB2) cursorF[i] = i * CAP;
        return;
    }

    const int row0  = blockIdx.x * 64;
    const int nrows = min(64, NN - row0);
    const int wid   = threadIdx.x >> 6;   // wave w computes relation w
    const int lane  = threadIdx.x & 63;

    float wreg[FF];
    {
        const float* Wr = W + (size_t)wid * FF * FF + lane;
#pragma unroll
        for (int k = 0; k < FF; ++k) wreg[k] = Wr[(size_t)k * FF];
    }

    unsigned short* Yp = Y + ((size_t)wid * NN + row0) * FF + lane;
    for (int row = 0; row < nrows; ++row) {
        // wave-uniform address -> scalar loads (SGPR operands for the FMAs)
        const float4* a4 = reinterpret_cast<const float4*>(inp + (size_t)(row0 + row) * FF);
        float acc0 = 0.f, acc1 = 0.f, acc2 = 0.f, acc3 = 0.f;
#pragma unroll
        for (int k4 = 0; k4 < FF / 4; ++k4) {
            const float4 a = a4[k4];
            acc0 = fmaf(a.x, wreg[4 * k4 + 0], acc0);
            acc1 = fmaf(a.y, wreg[4 * k4 + 1], acc1);
            acc2 = fmaf(a.z, wreg[4 * k4 + 2], acc2);
            acc3 = fmaf(a.w, wreg[4 * k4 + 3], acc3);
        }
        const float s = (acc0 + acc1) + (acc2 + acc3);
        unsigned int u = __float_as_uint(s);
        u += 0x7FFFu + ((u >> 16) & 1u);          // round-to-nearest-even
        Yp[(size_t)row * FF] = (unsigned short)(u >> 16);
    }
}

// ---------------------------------------------------------------------------
// Pass C (LDS-sorted burst writer, fixed-capacity buckets): each block stages
// its 12500-edge segment, counting-sorts it by fine bucket IN LDS (148 KB,
// 1 block/CU), reserves each bucket slice with one global atomicAdd on the
// bucket cursor (init = b*CAP), then streams out: consecutive threads write
// consecutive slots of each bucket run -> write-merge succeeds; only slice-
// boundary lines stay partial.
// rec.x = (d&63) << 19 | (plane*NN + src), rec.y = val bits.
__global__ __launch_bounds__(PC_T) void passC_scatter(const int* __restrict__ src,
                                                      const int* __restrict__ dst,
                                                      const float* __restrict__ val,
                                                      int* __restrict__ cursorF,
                                                      int2* __restrict__ recs) {
    __shared__ int2 srec[SEG];              // 100,000 B
    __shared__ unsigned short bkt[SEG];     // 25,000 B
    __shared__ int h[NB2];                  // 6,252 B
    __shared__ int sc[NB2];                 // 6,252 B
    __shared__ int sb[NB2];                 // 6,252 B
    __shared__ int s[PC_T];                 // 4,096 B   (~148 KB total)
    __shared__ int carry_s;

    const int base = blockIdx.x * SEG;
    const int tid  = threadIdx.x;

    for (int i = tid; i < NB2; i += PC_T) h[i] = 0;
    __syncthreads();

    // load segment to registers + rank via LDS atomics
    int2 my[MAXJ];
    int  rk[MAXJ];
    int  mb[MAXJ];
#pragma unroll
    for (int j = 0; j < MAXJ; ++j) {
        const int i = tid + j * PC_T;
        if (i < SEG) {
            const int e     = base + i;
            const int d     = dst[e];
            const int b     = d >> 6;
            const int plane = e / EE;             // const-div -> magic mul
            my[j] = make_int2(((d & 63) << IDXBITS) | (plane * NN + src[e]),
                              __float_as_int(val[e]));
            mb[j] = b;
            rk[j] = atomicAdd(&h[b], 1);
        }
    }
    __syncthreads();

    // exclusive scan of h -> sc (block scan with carry over 2 chunks)
    if (tid == 0) carry_s = 0;
    __syncthreads();
    for (int c = 0; c < NB2; c += PC_T) {
        const int i = c + tid;
        const int v = (i < NB2) ? h[i] : 0;
        s[tid] = v;
        __syncthreads();
        for (int d = 1; d < PC_T; d <<= 1) {
            int t = (tid >= d) ? s[tid - d] : 0;
            __syncthreads();
            s[tid] += t;
            __syncthreads();
        }
        if (i < NB2) sc[i] = s[tid] - v + carry_s;
        __syncthreads();
        if (tid == PC_T - 1) carry_s += s[PC_T - 1];
        __syncthreads();
    }

    // reserve global slices (one atomic per non-empty bucket)
    for (int i = tid; i < NB2; i += PC_T) {
        const int c = h[i];
        if (c) sb[i] = atomicAdd(&cursorF[i], c);
    }
    __syncthreads();

    // scatter into LDS in bucket-sorted order
#pragma unroll
    for (int j = 0; j < MAXJ; ++j) {
        const int i = tid + j * PC_T;
        if (i < SEG) {
            const int pos = sc[mb[j]] + rk[j];
            srec[pos] = my[j];
            bkt[pos]  = (unsigned short)mb[j];
        }
    }
    __syncthreads();

    // stream out: consecutive slots -> consecutive global positions per run
    for (int i = tid; i < SEG; i += PC_T) {
        const int b = bkt[i];
        recs[sb[b] + (i - sc[b])] = srec[i];
    }
}

// ---------------------------------------------------------------------------
// Fused sort+gather: one block per 64-node fine bucket. Bucket region is
// [b*CAP, cursorF[b]) (final cursor = fill level). CH=2048 (16 KB LDS).
// recs is streamed once -> non-temporal loads; out is write-once -> nt store.
__global__ __launch_bounds__(512, 8) void sort_gather(const int* __restrict__ cursorF,
                                                      const int2* __restrict__ recs,
                                                      const unsigned short* __restrict__ Y,
                                                      const float* __restrict__ bias,
                                                      float* __restrict__ out) {
    __shared__ int2 srec[CH];        // 16 KB
    __shared__ int  h[FB];
    __shared__ int  sc[FB];

    const int b    = blockIdx.x;     // fine bucket
    const int tid  = threadIdx.x;
    const int wid  = tid >> 6;       // 8 waves; wave handles 8 local nodes
    const int lane = tid & 63;
    const int beg  = b * CAP;
    const int end  = cursorF[b];

    const float bl = bias[lane] + bias[FF + lane] + bias[2 * FF + lane] + bias[3 * FF + lane];

    float acc[8];
#pragma unroll
    for (int i = 0; i < 8; ++i) acc[i] = 0.f;

    for (int cbeg = beg; cbeg < end; cbeg += CH) {
        const int m = min(CH, end - cbeg);

        if (tid < FB) h[tid] = 0;
        __syncthreads();

        // load chunk (non-temporal) + rank (register indices compile-time)
        int2 my[CH / 512];
        int  rk[CH / 512];
#pragma unroll
        for (int j = 0; j < CH / 512; ++j) {
            const int i = tid + j * 512;
            if (i < m) {
                const long long raw =
                    __builtin_nontemporal_load((const long long*)&recs[cbeg + i]);
                my[j] = make_int2((int)(unsigned int)raw, (int)(raw >> 32));
                rk[j] = atomicAdd(&h[(my[j].x >> IDXBITS) & (FB - 1)], 1);
            }
        }
        __syncthreads();

        // inclusive scan of h[0..63] by wave 0 via shfl
        if (tid < FB) {
            int v = h[tid];
#pragma unroll
            for (int d = 1; d < FB; d <<= 1) {
                const int t = __shfl_up(v, d, 64);
                if (tid >= d) v += t;
            }
            sc[tid] = v;
        }
        __syncthreads();

        // scatter into LDS in per-node order
#pragma unroll
        for (int j = 0; j < CH / 512; ++j) {
            const int i = tid + j * 512;
            if (i < m) {
                const int node = (my[j].x >> IDXBITS) & (FB - 1);
                srec[sc[node] - h[node] + rk[j]] = my[j];
            }
        }
        __syncthreads();

        // gather: wave wid owns local nodes [wid*8, wid*8+8)
#define YLD(R) __uint_as_float(((unsigned int)Y[(size_t)((R).x & IDXMASK) * FF + lane]) << 16)
#pragma unroll
        for (int ni = 0; ni < 8; ++ni) {
            const int node = wid * 8 + ni;
            const int s1   = sc[node];
            int       e    = s1 - h[node];
            float     a    = acc[ni];
            for (; e + 8 <= s1; e += 8) {
                const int2 r0 = srec[e],     r1 = srec[e + 1], r2 = srec[e + 2], r3 = srec[e + 3];
                const int2 r4 = srec[e + 4], r5 = srec[e + 5], r6 = srec[e + 6], r7 = srec[e + 7];
                const float y0 = YLD(r0), y1 = YLD(r1), y2 = YLD(r2), y3 = YLD(r3);
                const float y4 = YLD(r4), y5 = YLD(r5), y6 = YLD(r6), y7 = YLD(r7);
                a = fmaf(__int_as_float(r0.y), y0, a);
                a = fmaf(__int_as_float(r1.y), y1, a);
                a = fmaf(__int_as_float(r2.y), y2, a);
                a = fmaf(__int_as_float(r3.y), y3, a);
                a = fmaf(__int_as_float(r4.y), y4, a);
                a = fmaf(__int_as_float(r5.y), y5, a);
                a = fmaf(__int_as_float(r6.y), y6, a);
                a = fmaf(__int_as_float(r7.y), y7, a);
            }
            for (; e < s1; ++e) {
                const int2 r = srec[e];
                a = fmaf(__int_as_float(r.y), YLD(r), a);
            }
            acc[ni] = a;
        }
#undef YLD
        __syncthreads();   // LDS reused by next chunk
    }

    // store: 8 coalesced 256B rows per wave (non-temporal, never re-read)
#pragma unroll
    for (int ni = 0; ni < 8; ++ni) {
        const int g = b * FB + wid * 8 + ni;
        if (g < NN)
            __builtin_nontemporal_store(acc[ni] + bl, &out[(size_t)g * FF + lane]);
    }
}

// ---------------------------------------------------------------------------
// Fallback (round-1): f32 Y + atomic scatter straight to out.
__global__ __launch_bounds__(256) void init_out_kernel(const float* __restrict__ bias,
                                                       float* __restrict__ out) {
    int i = blockIdx.x * 256 + threadIdx.x;
    int j = i & (FF - 1);
    out[i] = bias[j] + bias[FF + j] + bias[2 * FF + j] + bias[3 * FF + j];
}

__global__ __launch_bounds__(256) void compute_y_f32(const float* __restrict__ inp,
                                                     const float* __restrict__ W,
                                                     float* __restrict__ Y) {
    __shared__ float s_inp[64 * FF];
    const int row0  = blockIdx.x * 64;
    const int nrows = min(64, NN - row0);
    {
        const float4* g  = reinterpret_cast<const float4*>(inp + (size_t)row0 * FF);
        float4*       s4 = reinterpret_cast<float4*>(s_inp);
        const int     nv4 = nrows * (FF / 4);
        for (int t = threadIdx.x; t < 64 * (FF / 4); t += 256)
            s4[t] = (t < nv4) ? g[t] : make_float4(0.f, 0.f, 0.f, 0.f);
    }
    __syncthreads();
    const int wid  = threadIdx.x >> 6;
    const int lane = threadIdx.x & 63;
    float wreg[FF];
    {
        const float* Wr = W + (size_t)wid * FF * FF + lane;
#pragma unroll
        for (int k = 0; k < FF; ++k) wreg[k] = Wr[(size_t)k * FF];
    }
    float* Yp = Y + ((size_t)wid * NN + row0) * FF + lane;
    for (int row = 0; row < nrows; ++row) {
        const float4* a4 = reinterpret_cast<const float4*>(s_inp + row * FF);
        float acc0 = 0.f, acc1 = 0.f, acc2 = 0.f, acc3 = 0.f;
#pragma unroll
        for (int k4 = 0; k4 < FF / 4; ++k4) {
            float4 a = a4[k4];
            acc0 = fmaf(a.x, wreg[4 * k4 + 0], acc0);
            acc1 = fmaf(a.y, wreg[4 * k4 + 1], acc1);
            acc2 = fmaf(a.z, wreg[4 * k4 + 2], acc2);
            acc3 = fmaf(a.w, wreg[4 * k4 + 3], acc3);
        }
        Yp[(size_t)row * FF] = (acc0 + acc1) + (acc2 + acc3);
    }
}

__global__ __launch_bounds__(256) void edge_scatter_kernel(const int* __restrict__ src,
                                                           const int* __restrict__ dst,
                                                           const float* __restrict__ val,
                                                           const float* __restrict__ Y,
                                                           float* __restrict__ out) {
    const int w = (blockIdx.x * 256 + threadIdx.x) >> 6;
    if (w >= NEDGE) return;
    const int   lane  = threadIdx.x & 63;
    const int   plane = w / EE;
    const float y     = Y[((size_t)(plane * NN + src[w])) * FF + lane];
    atomicAdd(out + (size_t)dst[w] * FF + lane, val[w] * y);
}

// ---------------------------------------------------------------------------
extern "C" void kernel_launch(void* const* d_in, const int* in_sizes, int n_in,
                              void* d_out, int out_size, void* d_ws, size_t ws_size,
                              hipStream_t stream) {
    const float* inp  = (const float*)d_in[0];
    const int*   src  = (const int*)d_in[1];
    const int*   dst  = (const int*)d_in[2];
    const float* val  = (const float*)d_in[3];
    const float* W    = (const float*)d_in[4];
    const float* bias = (const float*)d_in[5];
    float*       out  = (float*)d_out;
    char*        ws   = (char*)d_ws;

    // ws layout (8B-aligned)
    const size_t Y_OFF  = 0;
    const size_t Y_SZ   = (size_t)RR * NN * FF * sizeof(unsigned short);  // 51.2 MB
    const size_t R_OFF  = Y_OFF + Y_SZ;
    const size_t R_SZ   = (size_t)NB2 * CAP * sizeof(int2) + 65536;       // 57.7 MB (+pad)
    const size_t C_OFF  = R_OFF + R_SZ;
    const size_t C_SZ   = (size_t)NB2 * sizeof(int);
    const size_t TOTAL  = C_OFF + C_SZ;                                   // ~108.9 MB

    unsigned short* Ybf     = (unsigned short*)(ws + Y_OFF);
    int2*           recs    = (int2*)(ws + R_OFF);
    int*            cursorF = (int*)(ws + C_OFF);

    if (ws_size >= TOTAL) {
        compute_y_init<<<YB + CIB, 256, 0, stream>>>(inp, W, Ybf, cursorF);
        passC_scatter<<<PC_B, PC_T, 0, stream>>>(src, dst, val, cursorF, recs);
        sort_gather<<<NB2, 512, 0, stream>>>(cursorF, recs, Ybf, bias, out);
    } else {
        // Fallback: f32 Y + atomic scatter (round-1 path), needs 102.4 MB
        float* Yf = (float*)ws;
        init_out_kernel<<<(NN * FF) / 256, 256, 0, stream>>>(bias, out);
        compute_y_f32<<<(NN + 63) / 64, 256, 0, stream>>>(inp, W, Yf);
        edge_scatter_kernel<<<(NEDGE + 3) / 4, 256, 0, stream>>>(src, dst, val, Yf, out);
    }
}

// Round 19
// 293.622 us; speedup vs baseline: 1.1672x; 1.1672x over previous
//
#include <hip/hip_runtime.h>

// Problem constants (fixed by the harness's setup_inputs)
#define NN 100000   // nodes
#define EE 1600000  // edges per relation
#define RR 4        // relations
#define FF 64       // feature size (in == out == 64)
#define NEDGE (RR * EE)

#define FB 64                         // fine bucket = 64 nodes
#define NB2 ((NN + FB - 1) / FB)      // 1563 fine buckets (dst>>6)
#define CAP 4608                      // fixed bucket capacity (mean 4096 + 8 sigma)
#define YB ((NN + 63) / 64)           // 1563 Y-GEMM blocks
#define CIB ((NB2 + 255) / 256)       // 7 cursor-init tail blocks
#define PC_B 512                      // passC blocks
#define PC_T 1024                     // passC threads
#define SEG (NEDGE / PC_B)            // 12500 edges per passC block (exact)
#define MAXJ ((SEG + PC_T - 1) / PC_T)  // 13 regs per thread
#define IDXBITS 19                    // plane*NN+src < 400000 < 2^19
#define IDXMASK ((1 << IDXBITS) - 1)
#define CH 2048                       // recs per LDS chunk in sort_gather

// ---------------------------------------------------------------------------
// Blocks [0,YB): Y[r][n][j] = sum_k inp[n][k]*W[r][k][j], bf16 out (proven
// LDS-staged 256-thread/64-row shape: bulk coalesced prefetch + broadcast
// re-reads = the software pipeline that direct-global loads lack).
// Blocks [YB,YB+CIB): cursorF[b] = b*CAP (ready before passC launches).
__global__ __launch_bounds__(256) void compute_y_init(const float* __restrict__ inp,
                                                      const float* __restrict__ W,
                                                      unsigned short* __restrict__ Y,
                                                      int* __restrict__ cursorF) {
    if (blockIdx.x >= YB) {
        const int i = (blockIdx.x - YB) * 256 + threadIdx.x;
        if (i < NB2) cursorF[i] = i * CAP;
        return;
    }

    __shared__ float s_inp[64 * FF];   // 16 KB

    const int row0  = blockIdx.x * 64;
    const int nrows = min(64, NN - row0);
    {
        const float4* g  = reinterpret_cast<const float4*>(inp + (size_t)row0 * FF);
        float4*       s4 = reinterpret_cast<float4*>(s_inp);
        const int     nv4 = nrows * (FF / 4);
        for (int t = threadIdx.x; t < 64 * (FF / 4); t += 256)
            s4[t] = (t < nv4) ? g[t] : make_float4(0.f, 0.f, 0.f, 0.f);
    }
    __syncthreads();

    const int wid  = threadIdx.x >> 6;   // wave w computes relation w
    const int lane = threadIdx.x & 63;

    float wreg[FF];
    {
        const float* Wr = W + (size_t)wid * FF * FF + lane;
#pragma unroll
        for (int k = 0; k < FF; ++k) wreg[k] = Wr[(size_t)k * FF];
    }

    unsigned short* Yp = Y + ((size_t)wid * NN + row0) * FF + lane;
    for (int row = 0; row < nrows; ++row) {
        const float4* a4 = reinterpret_cast<const float4*>(s_inp + row * FF);
        float acc0 = 0.f, acc1 = 0.f, acc2 = 0.f, acc3 = 0.f;
#pragma unroll
        for (int k4 = 0; k4 < FF / 4; ++k4) {
            float4 a = a4[k4];  // wave-uniform -> LDS broadcast
            acc0 = fmaf(a.x, wreg[4 * k4 + 0], acc0);
            acc1 = fmaf(a.y, wreg[4 * k4 + 1], acc1);
            acc2 = fmaf(a.z, wreg[4 * k4 + 2], acc2);
            acc3 = fmaf(a.w, wreg[4 * k4 + 3], acc3);
        }
        const float s = (acc0 + acc1) + (acc2 + acc3);
        unsigned int u = __float_as_uint(s);
        u += 0x7FFFu + ((u >> 16) & 1u);          // round-to-nearest-even
        Yp[(size_t)row * FF] = (unsigned short)(u >> 16);
    }
}

// ---------------------------------------------------------------------------
// Pass C (LDS-sorted burst writer, fixed-capacity buckets): each block stages
// its 12500-edge segment, counting-sorts it by fine bucket IN LDS (148 KB,
// 1 block/CU), reserves each bucket slice with one global atomicAdd on the
// bucket cursor (init = b*CAP), then streams out: consecutive threads write
// consecutive slots of each bucket run -> write-merge succeeds; only slice-
// boundary lines stay partial.
// rec.x = (d&63) << 19 | (plane*NN + src), rec.y = val bits.
__global__ __launch_bounds__(PC_T) void passC_scatter(const int* __restrict__ src,
                                                      const int* __restrict__ dst,
                                                      const float* __restrict__ val,
                                                      int* __restrict__ cursorF,
                                                      int2* __restrict__ recs) {
    __shared__ int2 srec[SEG];              // 100,000 B
    __shared__ unsigned short bkt[SEG];     // 25,000 B
    __shared__ int h[NB2];                  // 6,252 B
    __shared__ int sc[NB2];                 // 6,252 B
    __shared__ int sb[NB2];                 // 6,252 B
    __shared__ int s[PC_T];                 // 4,096 B   (~148 KB total)
    __shared__ int carry_s;

    const int base = blockIdx.x * SEG;
    const int tid  = threadIdx.x;

    for (int i = tid; i < NB2; i += PC_T) h[i] = 0;
    __syncthreads();

    // load segment to registers + rank via LDS atomics
    int2 my[MAXJ];
    int  rk[MAXJ];
    int  mb[MAXJ];
#pragma unroll
    for (int j = 0; j < MAXJ; ++j) {
        const int i = tid + j * PC_T;
        if (i < SEG) {
            const int e     = base + i;
            const int d     = dst[e];
            const int b     = d >> 6;
            const int plane = e / EE;             // const-div -> magic mul
            my[j] = make_int2(((d & 63) << IDXBITS) | (plane * NN + src[e]),
                              __float_as_int(val[e]));
            mb[j] = b;
            rk[j] = atomicAdd(&h[b], 1);
        }
    }
    __syncthreads();

    // exclusive scan of h -> sc (block scan with carry over 2 chunks)
    if (tid == 0) carry_s = 0;
    __syncthreads();
    for (int c = 0; c < NB2; c += PC_T) {
        const int i = c + tid;
        const int v = (i < NB2) ? h[i] : 0;
        s[tid] = v;
        __syncthreads();
        for (int d = 1; d < PC_T; d <<= 1) {
            int t = (tid >= d) ? s[tid - d] : 0;
            __syncthreads();
            s[tid] += t;
            __syncthreads();
        }
        if (i < NB2) sc[i] = s[tid] - v + carry_s;
        __syncthreads();
        if (tid == PC_T - 1) carry_s += s[PC_T - 1];
        __syncthreads();
    }

    // reserve global slices (one atomic per non-empty bucket)
    for (int i = tid; i < NB2; i += PC_T) {
        const int c = h[i];
        if (c) sb[i] = atomicAdd(&cursorF[i], c);
    }
    __syncthreads();

    // scatter into LDS in bucket-sorted order
#pragma unroll
    for (int j = 0; j < MAXJ; ++j) {
        const int i = tid + j * PC_T;
        if (i < SEG) {
            const int pos = sc[mb[j]] + rk[j];
            srec[pos] = my[j];
            bkt[pos]  = (unsigned short)mb[j];
        }
    }
    __syncthreads();

    // stream out: consecutive slots -> consecutive global positions per run
    for (int i = tid; i < SEG; i += PC_T) {
        const int b = bkt[i];
        recs[sb[b] + (i - sc[b])] = srec[i];
    }
}

// ---------------------------------------------------------------------------
// Fused sort+gather: one block per 64-node fine bucket. Bucket region is
// [b*CAP, cursorF[b]) (final cursor = fill level). CH=2048 (16 KB LDS).
// recs is streamed once -> non-temporal loads; out is write-once -> nt store.
__global__ __launch_bounds__(512, 8) void sort_gather(const int* __restrict__ cursorF,
                                                      const int2* __restrict__ recs,
                                                      const unsigned short* __restrict__ Y,
                                                      const float* __restrict__ bias,
                                                      float* __restrict__ out) {
    __shared__ int2 srec[CH];        // 16 KB
    __shared__ int  h[FB];
    __shared__ int  sc[FB];

    const int b    = blockIdx.x;     // fine bucket
    const int tid  = threadIdx.x;
    const int wid  = tid >> 6;       // 8 waves; wave handles 8 local nodes
    const int lane = tid & 63;
    const int beg  = b * CAP;
    const int end  = cursorF[b];

    const float bl = bias[lane] + bias[FF + lane] + bias[2 * FF + lane] + bias[3 * FF + lane];

    float acc[8];
#pragma unroll
    for (int i = 0; i < 8; ++i) acc[i] = 0.f;

    for (int cbeg = beg; cbeg < end; cbeg += CH) {
        const int m = min(CH, end - cbeg);

        if (tid < FB) h[tid] = 0;
        __syncthreads();

        // load chunk (non-temporal) + rank (register indices compile-time)
        int2 my[CH / 512];
        int  rk[CH / 512];
#pragma unroll
        for (int j = 0; j < CH / 512; ++j) {
            const int i = tid + j * 512;
            if (i < m) {
                const long long raw =
                    __builtin_nontemporal_load((const long long*)&recs[cbeg + i]);
                my[j] = make_int2((int)(unsigned int)raw, (int)(raw >> 32));
                rk[j] = atomicAdd(&h[(my[j].x >> IDXBITS) & (FB - 1)], 1);
            }
        }
        __syncthreads();

        // inclusive scan of h[0..63] by wave 0 via shfl
        if (tid < FB) {
            int v = h[tid];
#pragma unroll
            for (int d = 1; d < FB; d <<= 1) {
                const int t = __shfl_up(v, d, 64);
                if (tid >= d) v += t;
            }
            sc[tid] = v;
        }
        __syncthreads();

        // scatter into LDS in per-node order
#pragma unroll
        for (int j = 0; j < CH / 512; ++j) {
            const int i = tid + j * 512;
            if (i < m) {
                const int node = (my[j].x >> IDXBITS) & (FB - 1);
                srec[sc[node] - h[node] + rk[j]] = my[j];
            }
        }
        __syncthreads();

        // gather: wave wid owns local nodes [wid*8, wid*8+8)
#define YLD(R) __uint_as_float(((unsigned int)Y[(size_t)((R).x & IDXMASK) * FF + lane]) << 16)
#pragma unroll
        for (int ni = 0; ni < 8; ++ni) {
            const int node = wid * 8 + ni;
            const int s1   = sc[node];
            int       e    = s1 - h[node];
            float     a    = acc[ni];
            for (; e + 8 <= s1; e += 8) {
                const int2 r0 = srec[e],     r1 = srec[e + 1], r2 = srec[e + 2], r3 = srec[e + 3];
                const int2 r4 = srec[e + 4], r5 = srec[e + 5], r6 = srec[e + 6], r7 = srec[e + 7];
                const float y0 = YLD(r0), y1 = YLD(r1), y2 = YLD(r2), y3 = YLD(r3);
                const float y4 = YLD(r4), y5 = YLD(r5), y6 = YLD(r6), y7 = YLD(r7);
                a = fmaf(__int_as_float(r0.y), y0, a);
                a = fmaf(__int_as_float(r1.y), y1, a);
                a = fmaf(__int_as_float(r2.y), y2, a);
                a = fmaf(__int_as_float(r3.y), y3, a);
                a = fmaf(__int_as_float(r4.y), y4, a);
                a = fmaf(__int_as_float(r5.y), y5, a);
                a = fmaf(__int_as_float(r6.y), y6, a);
                a = fmaf(__int_as_float(r7.y), y7, a);
            }
            for (; e < s1; ++e) {
                const int2 r = srec[e];
                a = fmaf(__int_as_float(r.y), YLD(r), a);
            }
            acc[ni] = a;
        }
#undef YLD
        __syncthreads();   // LDS reused by next chunk
    }

    // store: 8 coalesced 256B rows per wave (non-temporal, never re-read)
#pragma unroll
    for (int ni = 0; ni < 8; ++ni) {
        const int g = b * FB + wid * 8 + ni;
        if (g < NN)
            __builtin_nontemporal_store(acc[ni] + bl, &out[(size_t)g * FF + lane]);
    }
}

// ---------------------------------------------------------------------------
// Fallback (round-1): f32 Y + atomic scatter straight to out.
__global__ __launch_bounds__(256) void init_out_kernel(const float* __restrict__ bias,
                                                       float* __restrict__ out) {
    int i = blockIdx.x * 256 + threadIdx.x;
    int j = i & (FF - 1);
    out[i] = bias[j] + bias[FF + j] + bias[2 * FF + j] + bias[3 * FF + j];
}

__global__ __launch_bounds__(256) void compute_y_f32(const float* __restrict__ inp,
                                                     const float* __restrict__ W,
                                                     float* __restrict__ Y) {
    __shared__ float s_inp[64 * FF];
    const int row0  = blockIdx.x * 64;
    const int nrows = min(64, NN - row0);
    {
        const float4* g  = reinterpret_cast<const float4*>(inp + (size_t)row0 * FF);
        float4*       s4 = reinterpret_cast<float4*>(s_inp);
        const int     nv4 = nrows * (FF / 4);
        for (int t = threadIdx.x; t < 64 * (FF / 4); t += 256)
            s4[t] = (t < nv4) ? g[t] : make_float4(0.f, 0.f, 0.f, 0.f);
    }
    __syncthreads();
    const int wid  = threadIdx.x >> 6;
    const int lane = threadIdx.x & 63;
    float wreg[FF];
    {
        const float* Wr = W + (size_t)wid * FF * FF + lane;
#pragma unroll
        for (int k = 0; k < FF; ++k) wreg[k] = Wr[(size_t)k * FF];
    }
    float* Yp = Y + ((size_t)wid * NN + row0) * FF + lane;
    for (int row = 0; row < nrows; ++row) {
        const float4* a4 = reinterpret_cast<const float4*>(s_inp + row * FF);
        float acc0 = 0.f, acc1 = 0.f, acc2 = 0.f, acc3 = 0.f;
#pragma unroll
        for (int k4 = 0; k4 < FF / 4; ++k4) {
            float4 a = a4[k4];
            acc0 = fmaf(a.x, wreg[4 * k4 + 0], acc0);
            acc1 = fmaf(a.y, wreg[4 * k4 + 1], acc1);
            acc2 = fmaf(a.z, wreg[4 * k4 + 2], acc2);
            acc3 = fmaf(a.w, wreg[4 * k4 + 3], acc3);
        }
        Yp[(size_t)row * FF] = (acc0 + acc1) + (acc2 + acc3);
    }
}

__global__ __launch_bounds__(256) void edge_scatter_kernel(const int* __restrict__ src,
                                                           const int* __restrict__ dst,
                                                           const float* __restrict__ val,
                                                           const float* __restrict__ Y,
                                                           float* __restrict__ out) {
    const int w = (blockIdx.x * 256 + threadIdx.x) >> 6;
    if (w >= NEDGE) return;
    const int   lane  = threadIdx.x & 63;
    const int   plane = w / EE;
    const float y     = Y[((size_t)(plane * NN + src[w])) * FF + lane];
    atomicAdd(out + (size_t)dst[w] * FF + lane, val[w] * y);
}

// ---------------------------------------------------------------------------
extern "C" void kernel_launch(void* const* d_in, const int* in_sizes, int n_in,
                              void* d_out, int out_size, void* d_ws, size_t ws_size,
                              hipStream_t stream) {
    const float* inp  = (const float*)d_in[0];
    const int*   src  = (const int*)d_in[1];
    const int*   dst  = (const int*)d_in[2];
    const float* val  = (const float*)d_in[3];
    const float* W    = (const float*)d_in[4];
    const float* bias = (const float*)d_in[5];
    float*       out  = (float*)d_out;
    char*        ws   = (char*)d_ws;

    // ws layout (8B-aligned)
    const size_t Y_OFF  = 0;
    const size_t Y_SZ   = (size_t)RR * NN * FF * sizeof(unsigned short);  // 51.2 MB
    const size_t R_OFF  = Y_OFF + Y_SZ;
    const size_t R_SZ   = (size_t)NB2 * CAP * sizeof(int2) + 65536;       // 57.7 MB (+pad)
    const size_t C_OFF  = R_OFF + R_SZ;
    const size_t C_SZ   = (size_t)NB2 * sizeof(int);
    const size_t TOTAL  = C_OFF + C_SZ;                                   // ~108.9 MB

    unsigned short* Ybf     = (unsigned short*)(ws + Y_OFF);
    int2*           recs    = (int2*)(ws + R_OFF);
    int*            cursorF = (int*)(ws + C_OFF);

    if (ws_size >= TOTAL) {
        compute_y_init<<<YB + CIB, 256, 0, stream>>>(inp, W, Ybf, cursorF);
        passC_scatter<<<PC_B, PC_T, 0, stream>>>(src, dst, val, cursorF, recs);
        sort_gather<<<NB2, 512, 0, stream>>>(cursorF, recs, Ybf, bias, out);
    } else {
        // Fallback: f32 Y + atomic scatter (round-1 path), needs 102.4 MB
        float* Yf = (float*)ws;
        init_out_kernel<<<(NN * FF) / 256, 256, 0, stream>>>(bias, out);
        compute_y_f32<<<(NN + 63) / 64, 256, 0, stream>>>(inp, W, Yf);
        edge_scatter_kernel<<<(NEDGE + 3) / 4, 256, 0, stream>>>(src, dst, val, Yf, out);
    }
}